// Round 9
// baseline (29.528 us; speedup 1.0000x reference)
//
#include <hip/hip_runtime.h>
#include <stdint.h>

#define HW    56
#define CH    64
#define PIX   (HW*HW)      // 3136
#define KS    7
#define PAD   3
#define TS    8            // 8x8 spatial tile
#define HALO  14
#define HP    196
#define NPT   13           // ceil(196/16) MFMA row-tiles
#define XLD   68           // xs float stride
#define NCH   16           // channels per block (quadrant)
#define KVLD  17           // kv float2 stride
#define QLD   17           // q float stride

// LDS float offsets (kv/q alias dead xs region after P2)
#define F_Q    6664        // after kv: 196*17 float2 = 6664 floats
#define F_W    14144       // after xs: 208*68 = 14144 floats
#define F_REL  15680       // after W: 384 short8 = 1536 floats
#define F_TOT  15792       // 63,168 B -> 2 blocks/CU

typedef __attribute__((ext_vector_type(8))) short short8;
typedef __attribute__((ext_vector_type(4))) float f32x4;

__device__ __forceinline__ uint32_t rne_bf16(float v) {
    uint32_t u = __float_as_uint(v);
    return (u + 0x7FFFu + ((u >> 16) & 1u)) >> 16;
}
__device__ __forceinline__ float fexp2(float x) {
    float r;
    asm("v_exp_f32 %0, %1" : "=v"(r) : "v"(x));
    return r;
}

// grid 784 = 4 b * 49 tiles * 4 channel-quadrants, block 512 (8 waves)
__global__ __launch_bounds__(512, 4) void fused_attn(
    const float* __restrict__ x,  const float* __restrict__ Wq,
    const float* __restrict__ Wk, const float* __restrict__ Wv,
    const float* __restrict__ rel_h, const float* __restrict__ rel_w,
    float* __restrict__ out)
{
    __shared__ __align__(16) float lds[F_TOT];
    float2* kv = (float2*)lds;             // [px][c_local], after P2
    float*  xs = lds;                      // x halo [px][ci] (P1-P2)
    float*  ql = lds + F_Q;                // q [ip][c_local], pre-scaled log2e
    short8* wl = (short8*)(lds + F_W);     // W bf16 fragments (this quad only)
    float*  rl = lds + F_REL;              // rel slice [c_local][KS]

    // XCD-aware swizzle (784 % 8 == 0 -> bijective): same-tile quads co-locate
    const int orig = blockIdx.x;
    const int swz  = (orig & 7) * 98 + (orig >> 3);
    const int b    = swz / 196;
    const int rem  = swz % 196;
    const int tile = rem >> 2;
    const int quad = rem & 3;
    const int ty0  = (tile / 7) * TS;
    const int tx0  = (tile % 7) * TS;
    const int c0   = quad * NCH;
    const bool is_h = (quad < 2);          // block-uniform

    const int t = threadIdx.x;

    // ---- P1: stage x halo (fp32) + this quad's W frags + rel slice ----
    {
        const int hx = t & 15;             // 0..15, valid < 14
        const int u  = t >> 4;             // 0..31
        const int gx = tx0 + hx - PAD;
        const bool okx = (hx < HALO) & (gx >= 0) & (gx < HW);
        #pragma unroll
        for (int it = 0; it < 28; ++it) {
            int jj = u + 32 * it;          // 0..895 = gy*64 + ci
            int gy = jj >> 6;              // 0..13
            int ci = jj & 63;
            int iy = ty0 + gy - PAD;
            float v = 0.f;
            if (okx & (iy >= 0) & (iy < HW))
                v = x[(b * CH + ci) * PIX + iy * HW + gx];
            if (hx < HALO)
                xs[(gy * HALO + hx) * XLD + ci] = v;
        }
    }
    #pragma unroll
    for (int k = 0; k < 2; ++k) {          // zero garbage rows 196..207
        int u = t + 512 * k;
        if (u < 768)
            xs[(HP + (u >> 6)) * XLD + (u & 63)] = 0.f;
    }
    if (t < 384) {                         // W frags: 3 m * 2 ch * 64 lanes
        int m = t >> 7, ch = (t >> 6) & 1, l2 = t & 63;
        const float* Wm = (m == 0) ? Wk : (m == 1) ? Wv : Wq;
        const float* src = &Wm[(c0 + (l2 & 15)) * 64 + ch * 32 + (l2 >> 4) * 8];
        float4 f0 = *(const float4*)src;
        float4 f1 = *(const float4*)(src + 4);
        short8 h;
        h[0] = (short)rne_bf16(f0.x); h[1] = (short)rne_bf16(f0.y);
        h[2] = (short)rne_bf16(f0.z); h[3] = (short)rne_bf16(f0.w);
        h[4] = (short)rne_bf16(f1.x); h[5] = (short)rne_bf16(f1.y);
        h[6] = (short)rne_bf16(f1.z); h[7] = (short)rne_bf16(f1.w);
        wl[(m * 2 + ch) * 64 + l2] = h;
    }
    if (t < 112)                           // rel slice: 16 ch * 7
        rl[t] = is_h ? rel_h[(quad & 1) * 112 + t]
                     : rel_w[(quad - 2) * 112 + t];
    __syncthreads();

    // ---- P2: A-fragments (x split hi/lo bf16) into registers ----
    const int l  = t & 63;
    const int w  = t >> 6;                 // wave 0..7
    const int lr = l & 15;
    const int lk = l >> 4;

    short8 aH[2][2], aL[2][2];             // [slot][k-chunk]
    #pragma unroll
    for (int i = 0; i < 2; ++i) {
        int pt = w + 8 * i;
        if (pt < NPT) {
            int arow = pt * 16 + lr;       // <= 207 (rows 196+ zeroed)
            #pragma unroll
            for (int ch = 0; ch < 2; ++ch) {
                const float* src = &xs[arow * XLD + ch * 32 + lk * 8];
                float4 f0 = *(const float4*)src;
                float4 f1 = *(const float4*)(src + 4);
                float vv[8] = {f0.x, f0.y, f0.z, f0.w, f1.x, f1.y, f1.z, f1.w};
                short8 h, lo;
                #pragma unroll
                for (int j = 0; j < 8; ++j) {
                    uint32_t hb = rne_bf16(vv[j]);
                    h[j]  = (short)hb;
                    lo[j] = (short)rne_bf16(vv[j] - __uint_as_float(hb << 16));
                }
                aH[i][ch] = h; aL[i][ch] = lo;
            }
        }
    }
    __syncthreads();                       // xs dead; kv/ql may overwrite

    // ---- P3: k, v, q for this quad's 16 channels via MFMA ----
    #pragma unroll
    for (int m = 0; m < 3; ++m) {
        short8 bh0 = wl[(m * 2 + 0) * 64 + l];
        short8 bh1 = wl[(m * 2 + 1) * 64 + l];
        #pragma unroll
        for (int i = 0; i < 2; ++i) {
            int pt = w + 8 * i;
            if (pt < NPT) {
                f32x4 a = {0.f, 0.f, 0.f, 0.f};
                a = __builtin_amdgcn_mfma_f32_16x16x32_bf16(aL[i][0], bh0, a, 0, 0, 0);
                a = __builtin_amdgcn_mfma_f32_16x16x32_bf16(aH[i][0], bh0, a, 0, 0, 0);
                a = __builtin_amdgcn_mfma_f32_16x16x32_bf16(aL[i][1], bh1, a, 0, 0, 0);
                a = __builtin_amdgcn_mfma_f32_16x16x32_bf16(aH[i][1], bh1, a, 0, 0, 0);
                #pragma unroll
                for (int r = 0; r < 4; ++r) {
                    int px = pt * 16 + lk * 4 + r;
                    if (px < HP) {
                        if (m == 0)      kv[px * KVLD + lr].x = a[r];
                        else if (m == 1) kv[px * KVLD + lr].y = a[r];
                        else {
                            int py = px / HALO, pxx = px % HALO;
                            if (py >= PAD && py < PAD + TS &&
                                pxx >= PAD && pxx < PAD + TS)
                                ql[((py - PAD) * TS + (pxx - PAD)) * QLD + lr] =
                                    a[r] * 1.44269504088896f;
                        }
                    }
                }
            }
        }
    }
    __syncthreads();

    // ---- P4: per-channel windowed attention (2 outputs/thread) ----
    const int cc4 = t & 15;                // c_local
    const int oxb = ((t >> 4) & 3) * 2;    // ox base 0,2,4,6
    const int oyy = t >> 6;                // 0..7 (wave-uniform)

    float relv[KS];
    #pragma unroll
    for (int j = 0; j < KS; ++j)
        relv[j] = rl[cc4 * KS + j];

    float qv[2], sum[2] = {0.f, 0.f}, acc[2] = {0.f, 0.f}, racc[2] = {0.f, 0.f};
    qv[0] = ql[(oyy * TS + oxb) * QLD + cc4];
    qv[1] = ql[(oyy * TS + oxb + 1) * QLD + cc4];

    #pragma unroll
    for (int kh = 0; kh < KS; ++kh) {
        const int rb = (oyy + kh) * HALO + oxb;
        float2 row[8];
        #pragma unroll
        for (int ii = 0; ii < 8; ++ii)
            row[ii] = kv[(rb + ii) * KVLD + cc4];
        const float rh = relv[kh];
        if (is_h) {
            #pragma unroll
            for (int e = 0; e < 2; ++e) {
                float es = 0.f;
                #pragma unroll
                for (int kw = 0; kw < KS; ++kw) {
                    float ee = fexp2(qv[e] * row[e + kw].x);
                    es += ee;
                    acc[e] = fmaf(ee, row[e + kw].y, acc[e]);
                }
                sum[e] += es;
                racc[e] = fmaf(rh, es, racc[e]);
            }
        } else {
            #pragma unroll
            for (int e = 0; e < 2; ++e) {
                #pragma unroll
                for (int kw = 0; kw < KS; ++kw) {
                    float ee = fexp2(qv[e] * row[e + kw].x);
                    sum[e] += ee;
                    acc[e]  = fmaf(ee, row[e + kw].y, acc[e]);
                    racc[e] = fmaf(ee, relv[kw], racc[e]);
                }
            }
        }
    }
    __syncthreads();                       // kv/ql reads done

    // ---- P5: LDS transpose (reuse q region) + coalesced BCHW store ----
    float* os = ql;
    os[(oyy * TS + oxb)     * QLD + cc4] =
        (acc[0] + racc[0]) * __builtin_amdgcn_rcpf(sum[0]);
    os[(oyy * TS + oxb + 1) * QLD + cc4] =
        (acc[1] + racc[1]) * __builtin_amdgcn_rcpf(sum[1]);
    __syncthreads();
    #pragma unroll
    for (int k = 0; k < 2; ++k) {
        int idx = t + 512 * k;             // 0..1023 = cc*64 + p
        int p   = idx & 63;
        int cc  = idx >> 6;                // 0..15
        out[(b * CH + c0 + cc) * PIX + (ty0 + (p >> 3)) * HW + tx0 + (p & 7)] =
            os[p * QLD + cc];
    }
}

extern "C" void kernel_launch(void* const* d_in, const int* in_sizes, int n_in,
                              void* d_out, int out_size, void* d_ws, size_t ws_size,
                              hipStream_t stream) {
    const float* x     = (const float*)d_in[0];
    const float* Wq    = (const float*)d_in[1];
    const float* Wk    = (const float*)d_in[2];
    const float* Wv    = (const float*)d_in[3];
    const float* rel_h = (const float*)d_in[4];
    const float* rel_w = (const float*)d_in[5];
    float* out = (float*)d_out;

    fused_attn<<<784, 512, 0, stream>>>(x, Wq, Wk, Wv, rel_h, rel_w, out);
}

// Round 10
// 29.344 us; speedup vs baseline: 1.0063x; 1.0063x over previous
//
#include <hip/hip_runtime.h>
#include <stdint.h>

#define HW   56
#define CH   64
#define PIX  (HW*HW)       // 3136
#define NPIX (4*PIX)       // 12544
#define KS   7
#define PAD  3

typedef __attribute__((ext_vector_type(8))) short short8;
typedef __attribute__((ext_vector_type(4))) float f32x4;

__device__ __forceinline__ uint32_t rne_bf16(float v) {
    uint32_t u = __float_as_uint(v);
    return (u + 0x7FFFu + ((u >> 16) & 1u)) >> 16;
}
__device__ __forceinline__ float fexp2(float x) {
    float r;
    asm("v_exp_f32 %0, %1" : "=v"(r) : "v"(x));
    return r;
}

// ---------------- Kernel Q: q,k,v = 1x1 conv, NO halo, each px once --------
// grid 392 = 4 b * 98 chunks of 32 px, block 512 (8 waves).
// wave w: px-tile pt=w&1 (16 px), cot=w>>1 (16 out-ch). 12 MFMAs/wave.
// outputs: kvg float2 {k,v} [b*PIX+px][c]; qg fp32 pre-scaled by log2(e).
#define QXLD 68
__global__ __launch_bounds__(512, 4) void qkv_gemm(
    const float* __restrict__ x,  const float* __restrict__ Wq,
    const float* __restrict__ Wk, const float* __restrict__ Wv,
    float2* __restrict__ kvg, float* __restrict__ qg)
{
    __shared__ __align__(16) float  xs[32 * QXLD];   // 8.7 KB [px][ci]
    __shared__ __align__(16) short8 wl[1536];        // 24.6 KB W bf16 frags

    const int t   = threadIdx.x;
    const int b   = blockIdx.x / 98;
    const int px0 = (blockIdx.x % 98) * 32;

    #pragma unroll
    for (int i = 0; i < 4; ++i) {                    // stage x: coalesced
        int u = t + 512 * i;                         // 0..2047
        int ci = u >> 5, px = u & 31;
        xs[px * QXLD + ci] = x[(b * CH + ci) * PIX + px0 + px];
    }
    #pragma unroll
    for (int k = 0; k < 3; ++k) {                    // stage W frags (bf16)
        int u = t + 512 * k;
        if (u < 1536) {
            int m = u >> 9, cot = (u >> 7) & 3, ch = (u >> 6) & 1, l2 = u & 63;
            const float* Wm = (m == 0) ? Wk : (m == 1) ? Wv : Wq;
            const float* src = &Wm[(cot * 16 + (l2 & 15)) * 64 + ch * 32 + (l2 >> 4) * 8];
            float4 f0 = *(const float4*)src;
            float4 f1 = *(const float4*)(src + 4);
            short8 h;
            h[0] = (short)rne_bf16(f0.x); h[1] = (short)rne_bf16(f0.y);
            h[2] = (short)rne_bf16(f0.z); h[3] = (short)rne_bf16(f0.w);
            h[4] = (short)rne_bf16(f1.x); h[5] = (short)rne_bf16(f1.y);
            h[6] = (short)rne_bf16(f1.z); h[7] = (short)rne_bf16(f1.w);
            wl[u] = h;
        }
    }
    __syncthreads();

    const int l   = t & 63;
    const int w   = t >> 6;
    const int lr  = l & 15;
    const int lk  = l >> 4;
    const int pt  = w & 1;                           // px-tile 0..1
    const int cot = w >> 1;                          // 0..3

    const int arow = pt * 16 + lr;
    short8 aH[2], aL[2];
    #pragma unroll
    for (int ch = 0; ch < 2; ++ch) {
        const float* src = &xs[arow * QXLD + ch * 32 + lk * 8];
        float4 f0 = *(const float4*)src;
        float4 f1 = *(const float4*)(src + 4);
        float vv[8] = {f0.x, f0.y, f0.z, f0.w, f1.x, f1.y, f1.z, f1.w};
        short8 h, lo;
        #pragma unroll
        for (int j = 0; j < 8; ++j) {
            uint32_t hb = rne_bf16(vv[j]);
            h[j]  = (short)hb;
            lo[j] = (short)rne_bf16(vv[j] - __uint_as_float(hb << 16));
        }
        aH[ch] = h; aL[ch] = lo;
    }

    f32x4 res[3];
    #pragma unroll
    for (int m = 0; m < 3; ++m) {                    // m: 0=k, 1=v, 2=q
        short8 b0 = wl[((m * 4 + cot) * 2 + 0) * 64 + l];
        short8 b1 = wl[((m * 4 + cot) * 2 + 1) * 64 + l];
        f32x4 a = {0.f, 0.f, 0.f, 0.f};
        a = __builtin_amdgcn_mfma_f32_16x16x32_bf16(aL[0], b0, a, 0, 0, 0);
        a = __builtin_amdgcn_mfma_f32_16x16x32_bf16(aH[0], b0, a, 0, 0, 0);
        a = __builtin_amdgcn_mfma_f32_16x16x32_bf16(aL[1], b1, a, 0, 0, 0);
        a = __builtin_amdgcn_mfma_f32_16x16x32_bf16(aH[1], b1, a, 0, 0, 0);
        res[m] = a;
    }

    const int co = cot * 16 + lr;
    #pragma unroll
    for (int r = 0; r < 4; ++r) {
        const size_t g = (size_t)(b * PIX + px0 + pt * 16 + lk * 4 + r) * 64 + co;
        kvg[g] = make_float2(res[0][r], res[1][r]);  // coalesced 128B runs
        qg[g]  = res[2][r] * 1.44269504088896f;
    }
}

// ---------------- Kernel A: windowed per-channel attention ------------------
// grid 392 = 4 b * (7x14 tiles of 8x4), block 512 (8 waves), 74.6 KB -> 2/CU.
#define TH2   8
#define TW2   4
#define HLW   10
#define HPA   140          // 14*10 halo pixels
#define KLD   65           // fp32 stride, (p+c)%32 -> 2-way banks (free)

__global__ __launch_bounds__(512, 4) void attn_k(
    const float2* __restrict__ kvg, const float* __restrict__ qg,
    const float* __restrict__ rel_h, const float* __restrict__ rel_w,
    float* __restrict__ out)
{
    __shared__ __align__(16) float alds[2 * HPA * KLD + 448];
    float* kl = alds;                   // k [p][c] stride 65
    float* vl = alds + HPA * KLD;       // v [p][c] stride 65
    float* rl = alds + 2 * HPA * KLD;   // rel_h(224) ++ rel_w(224)

    // XCD swizzle (392 = 8*49, bijective): neighbor tiles share halo in L2
    const int blk  = blockIdx.x;
    const int swz  = (blk & 7) * 49 + (blk >> 3);
    const int b    = swz / 98;
    const int tile = swz % 98;
    const int ty0  = (tile / 14) * TH2;
    const int tx0  = (tile % 14) * TW2;

    const int t = threadIdx.x;
    const int l = t & 63;
    const int w = t >> 6;
    // is_h wave-uniform channel mapping
    const int c    = ((w & 1) << 5) | (l & 31);
    const int oy   = ((w >> 1) << 1) | (l >> 5);     // 0..7
    const bool is_h = ((w & 1) == 0);

    // q loads issued early (independent of LDS staging)
    float qv[TW2];
    #pragma unroll
    for (int ox = 0; ox < TW2; ++ox)
        qv[ox] = qg[(size_t)(b * PIX + (ty0 + oy) * HW + tx0 + ox) * 64 + c];

    for (int idx = t; idx < HPA * 64; idx += 512) {  // stage k,v halo
        int cc = idx & 63, p = idx >> 6;
        int hy = ty0 + p / HLW - PAD;
        int hx = tx0 + p % HLW - PAD;
        bool ok = (hy >= 0) & (hy < HW) & (hx >= 0) & (hx < HW);
        float2 f = ok ? kvg[(size_t)(b * PIX + hy * HW + hx) * 64 + cc]
                      : make_float2(0.f, 0.f);
        kl[p * KLD + cc] = f.x;
        vl[p * KLD + cc] = f.y;
    }
    if (t < 448) rl[t] = (t < 224) ? rel_h[t] : rel_w[t - 224];
    __syncthreads();

    float relv[KS];
    #pragma unroll
    for (int j = 0; j < KS; ++j)
        relv[j] = rl[(is_h ? 0 : 224) + (c & 31) * KS + j];

    float sum[TW2] = {0.f, 0.f, 0.f, 0.f};
    float acc[TW2] = {0.f, 0.f, 0.f, 0.f};
    float racc[TW2] = {0.f, 0.f, 0.f, 0.f};

    #pragma unroll
    for (int kh = 0; kh < KS; ++kh) {
        const int rb = (oy + kh) * HLW;
        float kr[HLW], vr[HLW];                      // row once, reused by 4 ox
        #pragma unroll
        for (int ii = 0; ii < HLW; ++ii) {
            kr[ii] = kl[(rb + ii) * KLD + c];
            vr[ii] = vl[(rb + ii) * KLD + c];
        }
        const float rh = relv[kh];
        if (is_h) {                                  // wave-uniform branch
            #pragma unroll
            for (int ox = 0; ox < TW2; ++ox) {
                float es = 0.f;
                #pragma unroll
                for (int kw = 0; kw < KS; ++kw) {
                    float e = fexp2(qv[ox] * kr[ox + kw]);
                    es += e;
                    acc[ox] = fmaf(e, vr[ox + kw], acc[ox]);
                }
                sum[ox] += es;
                racc[ox] = fmaf(rh, es, racc[ox]);
            }
        } else {
            #pragma unroll
            for (int ox = 0; ox < TW2; ++ox) {
                #pragma unroll
                for (int kw = 0; kw < KS; ++kw) {
                    float e = fexp2(qv[ox] * kr[ox + kw]);
                    sum[ox] += e;
                    acc[ox]  = fmaf(e, vr[ox + kw], acc[ox]);
                    racc[ox] = fmaf(e, relv[kw], racc[ox]);
                }
            }
        }
    }
    __syncthreads();                                 // all k/v reads done

    // transpose via LDS (reuse k region) + coalesced BCHW store
    float* os = alds;
    #pragma unroll
    for (int ox = 0; ox < TW2; ++ox)
        os[(oy * TW2 + ox) * KLD + c] =
            (acc[ox] + racc[ox]) * __builtin_amdgcn_rcpf(sum[ox]);
    __syncthreads();
    #pragma unroll
    for (int k = 0; k < 4; ++k) {
        int idx = t + 512 * k;                       // 0..2047 = cc*32 + p
        int p   = idx & 31;
        int cc  = idx >> 5;
        out[(b * CH + cc) * PIX + (ty0 + (p >> 2)) * HW + tx0 + (p & 3)] =
            os[p * KLD + cc];
    }
}

// ---------------- Fallback: naive fused (ws too small) ----------------------
__global__ __launch_bounds__(256) void naive_kernel(
    const float* __restrict__ x,  const float* __restrict__ Wq,
    const float* __restrict__ Wk, const float* __restrict__ Wv,
    const float* __restrict__ rel_h, const float* __restrict__ rel_w,
    float* __restrict__ out)
{
    int idx = blockIdx.x * 256 + threadIdx.x;
    if (idx >= NPIX * CH) return;
    int wpx = idx % HW;
    int hpx = (idx / HW) % HW;
    int c   = (idx / PIX) % CH;
    int b   = idx / (PIX * CH);
    const float* xb = x + (size_t)b * CH * PIX;

    float q = 0.f;
    for (int ci = 0; ci < CH; ++ci)
        q += Wq[c * CH + ci] * xb[ci * PIX + hpx * HW + wpx];

    float sum = 0.f, acc = 0.f;
    #pragma unroll
    for (int kh = 0; kh < KS; ++kh)
        #pragma unroll
        for (int kw = 0; kw < KS; ++kw) {
            int y = hpx + kh - PAD, xx = wpx + kw - PAD;
            float kv = 0.f, vv = 0.f;
            if (y >= 0 && y < HW && xx >= 0 && xx < HW)
                for (int ci = 0; ci < CH; ++ci) {
                    float xvv = xb[ci * PIX + y * HW + xx];
                    kv += Wk[c * CH + ci] * xvv;
                    vv += Wv[c * CH + ci] * xvv;
                }
            vv += (c < 32) ? rel_h[c * KS + kh] : rel_w[(c - 32) * KS + kw];
            float e = __expf(q * kv);
            sum += e;
            acc += e * vv;
        }
    out[idx] = acc / sum;
}

extern "C" void kernel_launch(void* const* d_in, const int* in_sizes, int n_in,
                              void* d_out, int out_size, void* d_ws, size_t ws_size,
                              hipStream_t stream) {
    const float* x     = (const float*)d_in[0];
    const float* Wq    = (const float*)d_in[1];
    const float* Wk    = (const float*)d_in[2];
    const float* Wv    = (const float*)d_in[3];
    const float* rel_h = (const float*)d_in[4];
    const float* rel_w = (const float*)d_in[5];
    float* out = (float*)d_out;

    const size_t arr  = (size_t)NPIX * CH;               // 802816
    const size_t need = arr * sizeof(float2) + arr * sizeof(float);  // 9.6 MB

    if (ws_size >= need) {
        float2* kvg = (float2*)d_ws;
        float*  qg  = (float*)(kvg + arr);
        qkv_gemm<<<392, 512, 0, stream>>>(x, Wq, Wk, Wv, kvg, qg);
        attn_k<<<392, 512, 0, stream>>>(kvg, qg, rel_h, rel_w, out);
    } else {
        naive_kernel<<<(NPIX * CH + 255) / 256, 256, 0, stream>>>(
            x, Wq, Wk, Wv, rel_h, rel_w, out);
    }
}